// Round 6
// baseline (190.504 us; speedup 1.0000x reference)
//
#include <hip/hip_runtime.h>
#include <hip/hip_bf16.h>
#include <cstdint>

typedef __bf16 bf16x8 __attribute__((ext_vector_type(8)));
typedef float f32x4 __attribute__((ext_vector_type(4)));

#define LDS_BYTES 131072   // 2 slots x 4 regions x 8192 elems x 2B
#define SLOT_E 32768

__device__ inline unsigned short f2bf(float f) {
  union { float f; unsigned u; } x; x.f = f;
  unsigned r = x.u + 0x7fffu + ((x.u >> 16) & 1u);
  return (unsigned short)(r >> 16);
}
__device__ inline float bf2f(unsigned short b) {
  union { unsigned u; float f; } x; x.u = ((unsigned)b) << 16;
  return x.f;
}

__device__ inline void gload_lds16(const void* g, void* l) {
  __builtin_amdgcn_global_load_lds(
      (const __attribute__((address_space(1))) unsigned int*)g,
      (__attribute__((address_space(3))) unsigned int*)l, 16, 0, 0);
}

// m201-style 8-phase GEMM: C = A * B^T (+bias). A[M,K], B[N,K] bf16, BK=64.
// BM=BN=256; 8 waves (2M x 4N), wave tile 128x64 (MI=8, NI=4), 64 MFMA/K-tile
// in 4 phases of 16. LDS: 2 dbuf x {A-lo, A-hi, B-lo, B-hi} regions, each
// [128][64], column XOR-swizzled: L(row,c) = G(row, c ^ ((row&7)<<3)).
// Read base for kk half: (kk*32+fk) ^ swz == (fk^swz) ^ (kk*32)  -> fb ^ 32
// for kk=1 (THE round-5 bug: fb+32 carried into bit 6 when swz bit5 set).
// One half-region staged per phase; vmcnt(6) once per K-tile (3 halves in
// flight, never drained mid-loop). Restage fences: every region's last reads
// are covered by a lgkmcnt(0) before the barrier preceding its restage.
// MODE 0: fused QKV (by>>2 = w: 0 K->C0, 1 Q->C1, 2 V->C2 transposed)
// MODE 2: scores bf16 = acc*scale, skip blocks above causal diagonal
// MODE 3: PV f32 = acc, K bounded to brow0+256
template <int MODE>
__global__ __launch_bounds__(512, 2) void gemm8(
    const unsigned short* __restrict__ A, int lda, long long sA,
    const unsigned short* __restrict__ B0, int ldb, long long sB,
    void* __restrict__ C0, int ldc, long long sC,
    const float* __restrict__ b0, const float* __restrict__ b1, const float* __restrict__ b2,
    void* __restrict__ C1, void* __restrict__ C2,
    int K, float scale)
{
  extern __shared__ unsigned short lds[];
  const int tid = threadIdx.x;
  const int wid = tid >> 6, lane = tid & 63;
  const int wr = wid >> 2, wc = wid & 3;
  const int frow = lane & 15, fk = (lane >> 4) * 8;

  const int bx = blockIdx.x, by = blockIdx.y, bz = blockIdx.z;
  const int brow0 = bx * 256;
  int bcol0, w = 0;
  const unsigned short *Ap, *Bp;
  if (MODE == 0) {
    w = by >> 2; bcol0 = (by & 3) * 256;
    Ap = A;
    Bp = B0 + ((size_t)w << 20);
  } else {
    bcol0 = by * 256;
    Ap = A + (size_t)bz * sA;
    Bp = B0 + (size_t)bz * sB;
    if (MODE == 2 && bcol0 > brow0 + 255) return;
  }
  const int kend = (MODE == 3) ? min(K, brow0 + 256) : K;
  const int nt = kend >> 6;

  // stage one half-region h (0=A-lo,1=A-hi,2=B-lo,3=B-hi) of tile t
  auto stageH = [&](int t, int h) {
    const int k0 = t << 6;
    unsigned short* dst = &lds[(t & 1) * SLOT_E + h * 8192];
    #pragma unroll
    for (int i = 0; i < 2; ++i) {
      const int e = (i * 512 + tid) * 8;
      const int r = e >> 6, c = e & 63;
      const int sc = k0 + (c ^ ((r & 7) << 3));   // pre-swizzled source col
      if (h < 2)
        gload_lds16(Ap + (size_t)(brow0 + h * 128 + r) * lda + sc, &dst[e]);
      else
        gload_lds16(Bp + (size_t)(bcol0 + (h - 2) * 128 + r) * ldb + sc, &dst[e]);
    }
  };

  f32x4 acc[8][4];
  #pragma unroll
  for (int i = 0; i < 8; ++i)
    #pragma unroll
    for (int j = 0; j < 4; ++j) acc[i][j] = (f32x4){0.f, 0.f, 0.f, 0.f};

  // per-thread fragment bases within a [128][64] region (swizzled read side)
  const int swz = (frow & 7) << 3;
  const int fb0 = frow * 64 + (fk ^ swz);   // kk=0
  const int fb1 = fb0 ^ 32;                 // kk=1: XOR 32, NOT +32

  // prologue: tile0 all 4 halves; tile1 halves 0-2; wait tile0 (6 loads out)
  stageH(0, 0); stageH(0, 1); stageH(0, 2); stageH(0, 3);
  if (1 < nt) {
    stageH(1, 0); stageH(1, 1); stageH(1, 2);
    asm volatile("s_waitcnt vmcnt(6)" ::: "memory");
  } else {
    asm volatile("s_waitcnt vmcnt(0)" ::: "memory");
  }
  __builtin_amdgcn_sched_barrier(0);
  __builtin_amdgcn_s_barrier();

#define PHASE_MFMA(KK, NB) do { \
    __builtin_amdgcn_s_setprio(1); \
    _Pragma("unroll") \
    for (int mi = 0; mi < 8; ++mi) { \
      acc[mi][NB]     = __builtin_amdgcn_mfma_f32_16x16x32_bf16(a[mi][KK], bfr[KK][NB],     acc[mi][NB], 0, 0, 0); \
      acc[mi][NB + 1] = __builtin_amdgcn_mfma_f32_16x16x32_bf16(a[mi][KK], bfr[KK][NB + 1], acc[mi][NB + 1], 0, 0, 0); \
    } \
    __builtin_amdgcn_s_setprio(0); \
  } while (0)

  #pragma unroll 1
  for (int t = 0; t < nt; ++t) {
    const unsigned short* sbA = &lds[(t & 1) * SLOT_E + wr * 8192];
    const unsigned short* sbB = &lds[(t & 1) * SLOT_E + 16384 + (wc >> 1) * 8192 + (wc & 1) * 4096];
    bf16x8 a[8][2], bfr[2][4];

    // ---- P1: all A reads + B kk0 reads; stage (t+1, B-hi); MFMA kk0 x n{0,1}
    #pragma unroll
    for (int mi = 0; mi < 8; ++mi) a[mi][0] = *(const bf16x8*)&sbA[mi * 1024 + fb0];
    #pragma unroll
    for (int ni = 0; ni < 4; ++ni) bfr[0][ni] = *(const bf16x8*)&sbB[ni * 1024 + fb0];
    #pragma unroll
    for (int mi = 0; mi < 8; ++mi) a[mi][1] = *(const bf16x8*)&sbA[mi * 1024 + fb1];
    if (t + 1 < nt) stageH(t + 1, 3);
    __builtin_amdgcn_s_barrier();
    asm volatile("s_waitcnt lgkmcnt(10)" ::: "memory");  // Ak0 + Bk0n01 ready
    __builtin_amdgcn_sched_barrier(0);
    PHASE_MFMA(0, 0);
    asm volatile("s_waitcnt lgkmcnt(0)" ::: "memory");   // ALL P1 reads done pre-barrier
    __builtin_amdgcn_sched_barrier(0);
    __builtin_amdgcn_s_barrier();

    // ---- P2: stage (t+2, A-lo); MFMA kk0 x n{2,3}
    if (t + 2 < nt) stageH(t + 2, 0);
    __builtin_amdgcn_s_barrier();
    PHASE_MFMA(0, 2);
    __builtin_amdgcn_s_barrier();

    // ---- P3: B kk1 reads; stage (t+2, A-hi); MFMA kk1 x n{0,1}
    #pragma unroll
    for (int ni = 0; ni < 4; ++ni) bfr[1][ni] = *(const bf16x8*)&sbB[ni * 1024 + fb1];
    if (t + 2 < nt) stageH(t + 2, 1);
    __builtin_amdgcn_s_barrier();
    asm volatile("s_waitcnt lgkmcnt(2)" ::: "memory");   // Bk1n01 ready
    __builtin_amdgcn_sched_barrier(0);
    PHASE_MFMA(1, 0);
    asm volatile("s_waitcnt lgkmcnt(0)" ::: "memory");   // all Bk1 done pre-barrier
    __builtin_amdgcn_sched_barrier(0);
    __builtin_amdgcn_s_barrier();

    // ---- P4: stage (t+2, B-lo); counted vmcnt; MFMA kk1 x n{2,3}
    if (t + 2 < nt) {
      stageH(t + 2, 2);
      asm volatile("s_waitcnt vmcnt(6)" ::: "memory");   // tile t+1 complete; t+2 in flight
    } else {
      asm volatile("s_waitcnt vmcnt(0)" ::: "memory");
    }
    __builtin_amdgcn_sched_barrier(0);
    __builtin_amdgcn_s_barrier();
    PHASE_MFMA(1, 2);
    __builtin_amdgcn_s_barrier();
  }
#undef PHASE_MFMA

  // epilogue: C/D layout col=lane&15, row=(lane>>4)*4+reg
  const float* bias = nullptr;
  if (MODE == 0) bias = (w == 0) ? b0 : (w == 1) ? b1 : b2;

  #pragma unroll
  for (int mi = 0; mi < 8; ++mi) {
    #pragma unroll
    for (int ni = 0; ni < 4; ++ni) {
      const int row0 = brow0 + wr * 128 + mi * 16 + (lane >> 4) * 4;
      const int col = bcol0 + wc * 64 + ni * 16 + frow;
      if (MODE == 0) {
        const float bv = bias[col];
        if (w == 2) {
          unsigned short* Cb = (unsigned short*)C2;
          const int bb = row0 >> 11, s0 = row0 & 2047;
          ushort4 pk;
          pk.x = f2bf(acc[mi][ni][0] + bv);
          pk.y = f2bf(acc[mi][ni][1] + bv);
          pk.z = f2bf(acc[mi][ni][2] + bv);
          pk.w = f2bf(acc[mi][ni][3] + bv);
          *(ushort4*)&Cb[(size_t)bb * (1024 * 2048) + (size_t)col * 2048 + s0] = pk;
        } else {
          unsigned short* Cb = (unsigned short*)(w == 0 ? C0 : C1);
          #pragma unroll
          for (int r = 0; r < 4; ++r)
            Cb[(size_t)(row0 + r) * ldc + col] = f2bf(acc[mi][ni][r] + bv);
        }
      } else if (MODE == 2) {
        unsigned short* Cb = (unsigned short*)C0 + (size_t)bz * sC;
        #pragma unroll
        for (int r = 0; r < 4; ++r)
          Cb[(size_t)(row0 + r) * ldc + col] = f2bf(acc[mi][ni][r] * scale);
      } else {
        float* Cf = (float*)C0 + (size_t)bz * sC;
        #pragma unroll
        for (int r = 0; r < 4; ++r)
          Cf[(size_t)(row0 + r) * ldc + col] = acc[mi][ni][r];
      }
    }
  }
}

// in-place causal softmax, trimmed to the 256-col-rounded causal prefix
// (PV with BM=256 reads exactly j < ((i>>8)+1)*256)
__global__ __launch_bounds__(256) void softmax_causal(unsigned short* __restrict__ Sc) {
  const int row = blockIdx.x;     // b*2048 + i
  const int i = row & 2047;
  const int nc = ((i >> 8) + 1) * 256;
  unsigned short* rp = Sc + (size_t)row * 2048;
  const int t = threadIdx.x;
  const int j0 = t * 8;
  const bool act = (j0 < nc);

  float v[8];
  if (act) {
    uint4 raw = ((const uint4*)rp)[t];
    unsigned us[8];
    us[0] = raw.x & 0xffffu; us[1] = raw.x >> 16;
    us[2] = raw.y & 0xffffu; us[3] = raw.y >> 16;
    us[4] = raw.z & 0xffffu; us[5] = raw.z >> 16;
    us[6] = raw.w & 0xffffu; us[7] = raw.w >> 16;
    #pragma unroll
    for (int e = 0; e < 8; ++e) v[e] = bf2f((unsigned short)us[e]);
  } else {
    #pragma unroll
    for (int e = 0; e < 8; ++e) v[e] = 0.f;
  }

  float m = -3.0e38f;
  if (act) {
    #pragma unroll
    for (int e = 0; e < 8; ++e) if (j0 + e <= i) m = fmaxf(m, v[e]);
  }
  #pragma unroll
  for (int o = 32; o > 0; o >>= 1) m = fmaxf(m, __shfl_xor(m, o));

  __shared__ float red[8];
  const int wid = t >> 6, lane = t & 63;
  if (lane == 0) red[wid] = m;
  __syncthreads();
  m = fmaxf(fmaxf(red[0], red[1]), fmaxf(red[2], red[3]));

  float ev[8];
  float s = 0.f;
  #pragma unroll
  for (int e = 0; e < 8; ++e) {
    float x = (act && j0 + e <= i) ? __expf(v[e] - m) : 0.f;
    ev[e] = x; s += x;
  }
  #pragma unroll
  for (int o = 32; o > 0; o >>= 1) s += __shfl_xor(s, o);
  if (lane == 0) red[4 + wid] = s;
  __syncthreads();
  s = red[4] + red[5] + red[6] + red[7];
  const float inv = 1.f / s;

  if (act) {
    uint4 outw;
    outw.x = (unsigned)f2bf(ev[0] * inv) | ((unsigned)f2bf(ev[1] * inv) << 16);
    outw.y = (unsigned)f2bf(ev[2] * inv) | ((unsigned)f2bf(ev[3] * inv) << 16);
    outw.z = (unsigned)f2bf(ev[4] * inv) | ((unsigned)f2bf(ev[5] * inv) << 16);
    outw.w = (unsigned)f2bf(ev[6] * inv) | ((unsigned)f2bf(ev[7] * inv) << 16);
    ((uint4*)rp)[t] = outw;
  }
}

__global__ __launch_bounds__(256) void cvt_f32_bf16(const float4* __restrict__ in,
                                                    ushort4* __restrict__ out, int n4) {
  const int idx = blockIdx.x * 256 + threadIdx.x;
  if (idx >= n4) return;
  float4 f = in[idx];
  ushort4 o;
  o.x = f2bf(f.x); o.y = f2bf(f.y); o.z = f2bf(f.z); o.w = f2bf(f.w);
  out[idx] = o;
}

__global__ __launch_bounds__(256) void cvt_w3(const float4* __restrict__ w0,
                                              const float4* __restrict__ w1,
                                              const float4* __restrict__ w2,
                                              ushort4* __restrict__ out) {
  const int g = blockIdx.x;            // [0,3072)
  const int sel = g >> 10;
  const int idx = (g & 1023) * 256 + threadIdx.x;
  const float4* in = (sel == 0) ? w0 : (sel == 1) ? w1 : w2;
  float4 f = in[idx];
  ushort4 o;
  o.x = f2bf(f.x); o.y = f2bf(f.y); o.z = f2bf(f.z); o.w = f2bf(f.w);
  out[(size_t)sel * 262144 + idx] = o;
}

extern "C" void kernel_launch(void* const* d_in, const int* in_sizes, int n_in,
                              void* d_out, int out_size, void* d_ws, size_t ws_size,
                              hipStream_t stream) {
  const float* x  = (const float*)d_in[0];
  const float* Wk = (const float*)d_in[1];
  const float* bk = (const float*)d_in[2];
  const float* Wq = (const float*)d_in[3];
  const float* bq = (const float*)d_in[4];
  const float* Wv = (const float*)d_in[5];
  const float* bv = (const float*)d_in[6];
  float* out = (float*)d_out;

  char* ws = (char*)d_ws;
  unsigned short* xb = (unsigned short*)(ws + 0);          // 8192x1024 bf16  (16 MB)
  unsigned short* Wb = (unsigned short*)(ws + 16777216);   // 3 x 1024x1024   (6 MB)
  unsigned short* Kb = (unsigned short*)(ws + 23068672);   // 8192x1024       (16 MB)
  unsigned short* Qb = (unsigned short*)(ws + 39845888);   // 8192x1024       (16 MB)
  unsigned short* Vt = (unsigned short*)(ws + 56623104);   // 4 x 1024x2048   (16 MB)
  unsigned short* Sc = (unsigned short*)(ws + 73400320);   // 4 x 2048x2048   (32 MB)

  (void)hipFuncSetAttribute(reinterpret_cast<const void*>(&gemm8<0>),
                            hipFuncAttributeMaxDynamicSharedMemorySize, LDS_BYTES);
  (void)hipFuncSetAttribute(reinterpret_cast<const void*>(&gemm8<2>),
                            hipFuncAttributeMaxDynamicSharedMemorySize, LDS_BYTES);
  (void)hipFuncSetAttribute(reinterpret_cast<const void*>(&gemm8<3>),
                            hipFuncAttributeMaxDynamicSharedMemorySize, LDS_BYTES);

  cvt_f32_bf16<<<8192, 256, 0, stream>>>((const float4*)x, (ushort4*)xb, 2097152);
  cvt_w3<<<3072, 256, 0, stream>>>((const float4*)Wk, (const float4*)Wq, (const float4*)Wv,
                                   (ushort4*)Wb);

  // fused QKV, 256x256 tiles: grid (32 row-blocks, 3 weights x 4 col-blocks)
  gemm8<0><<<dim3(32, 12, 1), 512, LDS_BYTES, stream>>>(
      xb, 1024, 0, Wb, 1024, 0, Kb, 1024, 0, bk, bq, bv, Qb, Vt, 1024, 1.f);

  // scores = Q K^T / 32, 256x256 tiles, causal lower-tri blocks only
  gemm8<2><<<dim3(8, 8, 4), 512, LDS_BYTES, stream>>>(
      Qb, 1024, 2048LL * 1024, Kb, 1024, 2048LL * 1024,
      Sc, 2048, 2048LL * 2048, nullptr, nullptr, nullptr, nullptr, nullptr, 1024, 0.03125f);

  softmax_causal<<<8192, 256, 0, stream>>>(Sc);

  // out = P @ V, 256x256 tiles, causal K-bound
  gemm8<3><<<dim3(8, 4, 4), 512, LDS_BYTES, stream>>>(
      Sc, 2048, 2048LL * 2048, Vt, 2048, 1024LL * 2048,
      out, 1024, 2048LL * 1024, nullptr, nullptr, nullptr, nullptr, nullptr, 2048, 1.f);
}

// Round 7
// 176.292 us; speedup vs baseline: 1.0806x; 1.0806x over previous
//
#include <hip/hip_runtime.h>
#include <hip/hip_bf16.h>
#include <cstdint>

typedef __bf16 bf16x8 __attribute__((ext_vector_type(8)));
typedef float f32x4 __attribute__((ext_vector_type(4)));

#define LDS_BYTES 131072   // 2 slots x 4 regions x 8192 elems x 2B
#define SLOT_E 32768

__device__ inline unsigned short f2bf(float f) {
  union { float f; unsigned u; } x; x.f = f;
  unsigned r = x.u + 0x7fffu + ((x.u >> 16) & 1u);
  return (unsigned short)(r >> 16);
}
__device__ inline float bf2f(unsigned short b) {
  union { unsigned u; float f; } x; x.u = ((unsigned)b) << 16;
  return x.f;
}

__device__ inline void gload_lds16(const void* g, void* l) {
  __builtin_amdgcn_global_load_lds(
      (const __attribute__((address_space(1))) unsigned int*)g,
      (__attribute__((address_space(3))) unsigned int*)l, 16, 0, 0);
}

// m201-anatomy 4-phase GEMM: C = A * B^T (+bias). A[M,K], B[N,K] bf16, BK=64.
// BM=BN=256; 8 waves (2M x 4N), wave tile 128x64 (MI=8, NI=4).
// Per K-tile: ph1{rd A.kk0(8)+B.kk0n01(2); stage B-lo(t+1)} ph2{rd B.kk0n23(2);
// stage B-hi(t+1)} ph3{rd A.kk1(8)+B.kk1n01(2)} ph4{rd B.kk1n23(2); stage
// A-lo,A-hi(t+2); vmcnt(4)}. Each phase: reads; stage; barrier; lgkmcnt(0);
// setprio(1); 16 MFMA; setprio(0); barrier. Region lifecycle: B(t+1) staged
// into NON-active slot (its old data was drained last iteration); A(t+2) into
// active slot after A(t)'s last reads (ph3) drained pre-ph3-MFMA + barrier.
// vmcnt ledger: at ph4, outstanding = B(t+1)[4] + A(t+2)[4] -> vmcnt(4)
// retires tile t+1 completely. Never drained mid-loop.
// LDS regions [128][64] col-XOR-swizzled: L(r,c)=G(r, c^((r&7)<<3));
// read base kk: (kk*32+fk)^swz = fb0 ^ (kk*32).
// MODE 0: fused QKV (by>>2 = w: 0 K->C0, 1 Q->C1, 2 V->C2 transposed)
// MODE 2: scores bf16 = acc*scale, skip blocks above causal diagonal
// MODE 3: PV f32, 1D grid with split-K (kend>1024 split; partials to C1/C2)
template <int MODE>
__global__ __launch_bounds__(512, 2) void gemm8(
    const unsigned short* __restrict__ A, int lda, long long sA,
    const unsigned short* __restrict__ B0, int ldb, long long sB,
    void* __restrict__ C0, int ldc, long long sC,
    const float* __restrict__ b0, const float* __restrict__ b1, const float* __restrict__ b2,
    void* __restrict__ C1, void* __restrict__ C2,
    int K, float scale)
{
  extern __shared__ unsigned short lds[];
  const int tid = threadIdx.x;
  const int wid = tid >> 6, lane = tid & 63;
  const int wr = wid >> 2, wc = wid & 3;
  const int frow = lane & 15, fk = (lane >> 4) * 8;

  int bx, by, bz, w = 0, half = 0, split = 0, kbeg = 0, kend;
  if (MODE == 3) {
    const int id = blockIdx.x;          // 192 blocks
    bz = id & 3; by = (id >> 2) & 3;
    const int s = id >> 4;              // [0,12)
    if (s < 4) { bx = s; kbeg = 0; kend = 256 * (s + 1); }
    else {
      bx = 4 + ((s - 4) >> 1); half = (s - 4) & 1; split = 1;
      kbeg = half ? 1024 : 0;
      kend = half ? 256 * (bx + 1) : 1024;
    }
  } else {
    bx = blockIdx.x; by = blockIdx.y; bz = blockIdx.z;
    kend = K;
  }
  const int brow0 = bx * 256;
  int bcol0;
  const unsigned short *Ap, *Bp;
  if (MODE == 0) {
    w = by >> 2; bcol0 = (by & 3) * 256;
    Ap = A;
    Bp = B0 + ((size_t)w << 20);
  } else {
    bcol0 = by * 256;
    Ap = A + (size_t)bz * sA + kbeg;
    Bp = B0 + (size_t)bz * sB + kbeg;
    if (MODE == 2 && bcol0 > brow0 + 255) return;
  }
  const int nt = (kend - kbeg) >> 6;

  // stage one half-region h (0=A-lo,1=A-hi,2=B-lo,3=B-hi) of tile t (2 gloads)
  auto stageH = [&](int t, int h) {
    const int k0 = t << 6;
    unsigned short* dst = &lds[(t & 1) * SLOT_E + h * 8192];
    #pragma unroll
    for (int i = 0; i < 2; ++i) {
      const int e = (i * 512 + tid) * 8;
      const int r = e >> 6, c = e & 63;
      const int sc = k0 + (c ^ ((r & 7) << 3));   // pre-swizzled source col
      if (h < 2)
        gload_lds16(Ap + (size_t)(brow0 + h * 128 + r) * lda + sc, &dst[e]);
      else
        gload_lds16(Bp + (size_t)(bcol0 + (h - 2) * 128 + r) * ldb + sc, &dst[e]);
    }
  };

  f32x4 acc[8][4];
  #pragma unroll
  for (int i = 0; i < 8; ++i)
    #pragma unroll
    for (int j = 0; j < 4; ++j) acc[i][j] = (f32x4){0.f, 0.f, 0.f, 0.f};

  const int swz = (frow & 7) << 3;
  const int fb0 = frow * 64 + (fk ^ swz);   // kk=0 read base
  const int fb1 = fb0 ^ 32;                 // kk=1: XOR 32 (not +32)

  // prologue: tile0 all 4 halves; tile1 A halves; vmcnt(4) = tile0 landed
  stageH(0, 0); stageH(0, 1); stageH(0, 2); stageH(0, 3);
  if (1 < nt) {
    stageH(1, 0); stageH(1, 1);
    asm volatile("s_waitcnt vmcnt(4)" ::: "memory");
  } else {
    asm volatile("s_waitcnt vmcnt(0)" ::: "memory");
  }
  __builtin_amdgcn_sched_barrier(0);
  __builtin_amdgcn_s_barrier();

#define MFMA16(AV, NB) do { \
    __builtin_amdgcn_s_setprio(1); \
    _Pragma("unroll") \
    for (int mi = 0; mi < 8; ++mi) { \
      acc[mi][NB]     = __builtin_amdgcn_mfma_f32_16x16x32_bf16(AV[mi], bq0, acc[mi][NB], 0, 0, 0); \
      acc[mi][NB + 1] = __builtin_amdgcn_mfma_f32_16x16x32_bf16(AV[mi], bq1, acc[mi][NB + 1], 0, 0, 0); \
    } \
    __builtin_amdgcn_s_setprio(0); \
  } while (0)

  #pragma unroll 1
  for (int t = 0; t < nt; ++t) {
    const unsigned short* sbA = &lds[(t & 1) * SLOT_E + wr * 8192];
    const unsigned short* sbB = &lds[(t & 1) * SLOT_E + 16384 + (wc >> 1) * 8192 + (wc & 1) * 4096];
    bf16x8 a0[8], a1[8], bq0, bq1;

    // ---- ph1: A.kk0 (8) + B.kk0 n01 (2); stage B-lo(t+1) ----
    #pragma unroll
    for (int mi = 0; mi < 8; ++mi) a0[mi] = *(const bf16x8*)&sbA[mi * 1024 + fb0];
    bq0 = *(const bf16x8*)&sbB[fb0];
    bq1 = *(const bf16x8*)&sbB[1024 + fb0];
    if (t + 1 < nt) stageH(t + 1, 2);
    __builtin_amdgcn_sched_barrier(0);
    __builtin_amdgcn_s_barrier();
    asm volatile("s_waitcnt lgkmcnt(0)" ::: "memory");
    __builtin_amdgcn_sched_barrier(0);
    MFMA16(a0, 0);
    __builtin_amdgcn_s_barrier();

    // ---- ph2: B.kk0 n23 (2); stage B-hi(t+1) ----
    bq0 = *(const bf16x8*)&sbB[2048 + fb0];
    bq1 = *(const bf16x8*)&sbB[3072 + fb0];
    if (t + 1 < nt) stageH(t + 1, 3);
    __builtin_amdgcn_sched_barrier(0);
    __builtin_amdgcn_s_barrier();
    asm volatile("s_waitcnt lgkmcnt(0)" ::: "memory");
    __builtin_amdgcn_sched_barrier(0);
    MFMA16(a0, 2);
    __builtin_amdgcn_s_barrier();

    // ---- ph3: A.kk1 (8) + B.kk1 n01 (2) ----
    #pragma unroll
    for (int mi = 0; mi < 8; ++mi) a1[mi] = *(const bf16x8*)&sbA[mi * 1024 + fb1];
    bq0 = *(const bf16x8*)&sbB[fb1];
    bq1 = *(const bf16x8*)&sbB[1024 + fb1];
    __builtin_amdgcn_sched_barrier(0);
    __builtin_amdgcn_s_barrier();
    asm volatile("s_waitcnt lgkmcnt(0)" ::: "memory");
    __builtin_amdgcn_sched_barrier(0);
    MFMA16(a1, 0);
    __builtin_amdgcn_s_barrier();

    // ---- ph4: B.kk1 n23 (2); stage A-lo,A-hi(t+2); vmcnt(4) ----
    bq0 = *(const bf16x8*)&sbB[2048 + fb1];
    bq1 = *(const bf16x8*)&sbB[3072 + fb1];
    if (t + 2 < nt) {
      stageH(t + 2, 0); stageH(t + 2, 1);
      asm volatile("s_waitcnt vmcnt(4)" ::: "memory");   // tile t+1 fully landed
    } else {
      asm volatile("s_waitcnt vmcnt(0)" ::: "memory");
    }
    __builtin_amdgcn_sched_barrier(0);
    __builtin_amdgcn_s_barrier();
    asm volatile("s_waitcnt lgkmcnt(0)" ::: "memory");
    __builtin_amdgcn_sched_barrier(0);
    MFMA16(a1, 2);
    __builtin_amdgcn_s_barrier();
  }
#undef MFMA16

  // epilogue: C/D layout col=lane&15, row=(lane>>4)*4+reg
  const float* bias = nullptr;
  if (MODE == 0) bias = (w == 0) ? b0 : (w == 1) ? b1 : b2;

  #pragma unroll
  for (int mi = 0; mi < 8; ++mi) {
    #pragma unroll
    for (int ni = 0; ni < 4; ++ni) {
      const int row0 = brow0 + wr * 128 + mi * 16 + (lane >> 4) * 4;
      const int col = bcol0 + wc * 64 + ni * 16 + frow;
      if (MODE == 0) {
        const float bv = bias[col];
        if (w == 2) {
          unsigned short* Cb = (unsigned short*)C2;
          const int bb = row0 >> 11, s0 = row0 & 2047;
          ushort4 pk;
          pk.x = f2bf(acc[mi][ni][0] + bv);
          pk.y = f2bf(acc[mi][ni][1] + bv);
          pk.z = f2bf(acc[mi][ni][2] + bv);
          pk.w = f2bf(acc[mi][ni][3] + bv);
          *(ushort4*)&Cb[(size_t)bb * (1024 * 2048) + (size_t)col * 2048 + s0] = pk;
        } else {
          unsigned short* Cb = (unsigned short*)(w == 0 ? C0 : C1);
          #pragma unroll
          for (int r = 0; r < 4; ++r)
            Cb[(size_t)(row0 + r) * ldc + col] = f2bf(acc[mi][ni][r] + bv);
        }
      } else if (MODE == 2) {
        unsigned short* Cb = (unsigned short*)C0 + (size_t)bz * sC;
        #pragma unroll
        for (int r = 0; r < 4; ++r)
          Cb[(size_t)(row0 + r) * ldc + col] = f2bf(acc[mi][ni][r] * scale);
      } else {
        float* Cf;
        int rr;
        if (!split) { Cf = (float*)C0 + (size_t)bz * sC; rr = row0; }
        else {
          Cf = (float*)(half ? C2 : C1) + (size_t)bz * (1024 * 1024);
          rr = row0 - 1024;
        }
        #pragma unroll
        for (int r = 0; r < 4; ++r)
          Cf[(size_t)(rr + r) * ldc + col] = acc[mi][ni][r];
      }
    }
  }
}

// out rows 1024-2047 = Pw0 + Pw1 (split-K reduction), float4-wide
__global__ __launch_bounds__(256) void addpv(const float4* __restrict__ p0,
                                             const float4* __restrict__ p1,
                                             float4* __restrict__ out) {
  const int g = blockIdx.x * 256 + threadIdx.x;   // [0, 1048576)
  const int bz = g >> 18, rem = g & 262143;
  float4 a = p0[g], b = p1[g];
  float4 o = {a.x + b.x, a.y + b.y, a.z + b.z, a.w + b.w};
  out[(size_t)bz * 524288 + 262144 + rem] = o;
}

// in-place causal softmax, trimmed to the 256-col-rounded causal prefix
__global__ __launch_bounds__(256) void softmax_causal(unsigned short* __restrict__ Sc) {
  const int row = blockIdx.x;     // b*2048 + i
  const int i = row & 2047;
  const int nc = ((i >> 8) + 1) * 256;
  unsigned short* rp = Sc + (size_t)row * 2048;
  const int t = threadIdx.x;
  const int j0 = t * 8;
  const bool act = (j0 < nc);

  float v[8];
  if (act) {
    uint4 raw = ((const uint4*)rp)[t];
    unsigned us[8];
    us[0] = raw.x & 0xffffu; us[1] = raw.x >> 16;
    us[2] = raw.y & 0xffffu; us[3] = raw.y >> 16;
    us[4] = raw.z & 0xffffu; us[5] = raw.z >> 16;
    us[6] = raw.w & 0xffffu; us[7] = raw.w >> 16;
    #pragma unroll
    for (int e = 0; e < 8; ++e) v[e] = bf2f((unsigned short)us[e]);
  } else {
    #pragma unroll
    for (int e = 0; e < 8; ++e) v[e] = 0.f;
  }

  float m = -3.0e38f;
  if (act) {
    #pragma unroll
    for (int e = 0; e < 8; ++e) if (j0 + e <= i) m = fmaxf(m, v[e]);
  }
  #pragma unroll
  for (int o = 32; o > 0; o >>= 1) m = fmaxf(m, __shfl_xor(m, o));

  __shared__ float red[8];
  const int wid = t >> 6, lane = t & 63;
  if (lane == 0) red[wid] = m;
  __syncthreads();
  m = fmaxf(fmaxf(red[0], red[1]), fmaxf(red[2], red[3]));

  float ev[8];
  float s = 0.f;
  #pragma unroll
  for (int e = 0; e < 8; ++e) {
    float x = (act && j0 + e <= i) ? __expf(v[e] - m) : 0.f;
    ev[e] = x; s += x;
  }
  #pragma unroll
  for (int o = 32; o > 0; o >>= 1) s += __shfl_xor(s, o);
  if (lane == 0) red[4 + wid] = s;
  __syncthreads();
  s = red[4] + red[5] + red[6] + red[7];
  const float inv = 1.f / s;

  if (act) {
    uint4 outw;
    outw.x = (unsigned)f2bf(ev[0] * inv) | ((unsigned)f2bf(ev[1] * inv) << 16);
    outw.y = (unsigned)f2bf(ev[2] * inv) | ((unsigned)f2bf(ev[3] * inv) << 16);
    outw.z = (unsigned)f2bf(ev[4] * inv) | ((unsigned)f2bf(ev[5] * inv) << 16);
    outw.w = (unsigned)f2bf(ev[6] * inv) | ((unsigned)f2bf(ev[7] * inv) << 16);
    ((uint4*)rp)[t] = outw;
  }
}

__global__ __launch_bounds__(256) void cvt_f32_bf16(const float4* __restrict__ in,
                                                    ushort4* __restrict__ out, int n4) {
  const int idx = blockIdx.x * 256 + threadIdx.x;
  if (idx >= n4) return;
  float4 f = in[idx];
  ushort4 o;
  o.x = f2bf(f.x); o.y = f2bf(f.y); o.z = f2bf(f.z); o.w = f2bf(f.w);
  out[idx] = o;
}

__global__ __launch_bounds__(256) void cvt_w3(const float4* __restrict__ w0,
                                              const float4* __restrict__ w1,
                                              const float4* __restrict__ w2,
                                              ushort4* __restrict__ out) {
  const int g = blockIdx.x;            // [0,3072)
  const int sel = g >> 10;
  const int idx = (g & 1023) * 256 + threadIdx.x;
  const float4* in = (sel == 0) ? w0 : (sel == 1) ? w1 : w2;
  float4 f = in[idx];
  ushort4 o;
  o.x = f2bf(f.x); o.y = f2bf(f.y); o.z = f2bf(f.z); o.w = f2bf(f.w);
  out[(size_t)sel * 262144 + idx] = o;
}

extern "C" void kernel_launch(void* const* d_in, const int* in_sizes, int n_in,
                              void* d_out, int out_size, void* d_ws, size_t ws_size,
                              hipStream_t stream) {
  const float* x  = (const float*)d_in[0];
  const float* Wk = (const float*)d_in[1];
  const float* bk = (const float*)d_in[2];
  const float* Wq = (const float*)d_in[3];
  const float* bq = (const float*)d_in[4];
  const float* Wv = (const float*)d_in[5];
  const float* bv = (const float*)d_in[6];
  float* out = (float*)d_out;

  char* ws = (char*)d_ws;
  unsigned short* xb = (unsigned short*)(ws + 0);          // 8192x1024 bf16  (16 MB)
  unsigned short* Wb = (unsigned short*)(ws + 16777216);   // 3 x 1024x1024   (6 MB)
  unsigned short* Kb = (unsigned short*)(ws + 23068672);   // 8192x1024       (16 MB)
  unsigned short* Qb = (unsigned short*)(ws + 39845888);   // 8192x1024       (16 MB)
  unsigned short* Vt = (unsigned short*)(ws + 56623104);   // 4 x 1024x2048   (16 MB)
  unsigned short* Sc = (unsigned short*)(ws + 73400320);   // 4 x 2048x2048   (32 MB)
  // split-K partials reuse Qb/Kb (dead after scores): 4x1024x1024 f32 each
  float* Pw0 = (float*)Kb;
  float* Pw1 = (float*)Qb;

  (void)hipFuncSetAttribute(reinterpret_cast<const void*>(&gemm8<0>),
                            hipFuncAttributeMaxDynamicSharedMemorySize, LDS_BYTES);
  (void)hipFuncSetAttribute(reinterpret_cast<const void*>(&gemm8<2>),
                            hipFuncAttributeMaxDynamicSharedMemorySize, LDS_BYTES);
  (void)hipFuncSetAttribute(reinterpret_cast<const void*>(&gemm8<3>),
                            hipFuncAttributeMaxDynamicSharedMemorySize, LDS_BYTES);

  cvt_f32_bf16<<<8192, 256, 0, stream>>>((const float4*)x, (ushort4*)xb, 2097152);
  cvt_w3<<<3072, 256, 0, stream>>>((const float4*)Wk, (const float4*)Wq, (const float4*)Wv,
                                   (ushort4*)Wb);

  // fused QKV, 256x256 tiles: grid (32 row-blocks, 3 weights x 4 col-blocks)
  gemm8<0><<<dim3(32, 12, 1), 512, LDS_BYTES, stream>>>(
      xb, 1024, 0, Wb, 1024, 0, Kb, 1024, 0, bk, bq, bv, Qb, Vt, 1024, 1.f);

  // scores = Q K^T / 32, 256x256 tiles, causal lower-tri blocks only
  gemm8<2><<<dim3(8, 8, 4), 512, LDS_BYTES, stream>>>(
      Qb, 1024, 2048LL * 1024, Kb, 1024, 2048LL * 1024,
      Sc, 2048, 2048LL * 2048, nullptr, nullptr, nullptr, nullptr, nullptr, 1024, 0.03125f);

  softmax_causal<<<8192, 256, 0, stream>>>(Sc);

  // out = P @ V, 256x256 tiles, split-K (kend>1024 -> two halves), 192 blocks
  gemm8<3><<<dim3(192, 1, 1), 512, LDS_BYTES, stream>>>(
      Sc, 2048, 2048LL * 2048, Vt, 2048, 1024LL * 2048,
      out, 1024, 2048LL * 1024, nullptr, nullptr, nullptr, Pw0, Pw1, 2048, 1.f);

  // reduce split-K partials into out rows 1024-2047
  addpv<<<4096, 256, 0, stream>>>((const float4*)Pw0, (const float4*)Pw1, (float4*)out);
}

// Round 9
// 144.330 us; speedup vs baseline: 1.3199x; 1.2214x over previous
//
#include <hip/hip_runtime.h>
#include <hip/hip_bf16.h>
#include <cstdint>

typedef __bf16 bf16x8 __attribute__((ext_vector_type(8)));
typedef float f32x4 __attribute__((ext_vector_type(4)));

__device__ inline unsigned short f2bf(float f) {
  union { float f; unsigned u; } x; x.f = f;
  unsigned r = x.u + 0x7fffu + ((x.u >> 16) & 1u);
  return (unsigned short)(r >> 16);
}
__device__ inline float bf2f(unsigned short b) {
  union { unsigned u; float f; } x; x.u = ((unsigned)b) << 16;
  return x.f;
}

__device__ inline void gload_lds16(const void* g, void* l) {
  __builtin_amdgcn_global_load_lds(
      (const __attribute__((address_space(1))) unsigned int*)g,
      (__attribute__((address_space(3))) unsigned int*)l, 16, 0, 0);
}

// m97-structure GEMM: C = A * B^T (+bias). A[M,K], B[N,K] bf16, BM=BN=128,
// BK=64, 256 threads (4 waves 2x2, wave tile 64x64, acc[4][4]).
// 32 KB single-buffer LDS, 2 barriers/K-step; stalls hidden by co-resident
// blocks/CU (m114 TLP mechanism), NOT by in-block pipelining.
// LDS [128][64] col-XOR-swizzled: L(r,c)=G(r, c^((r&7)<<3)) (proven r2/r3);
// staged linearly via pre-swizzled global source col.
// Grids are 1D with XCD-aware decode (hardware XCD ~ blockIdx.x % 8):
//  MODE 0 QKV: 1536 blocks. x=id&7, k=id>>3: bx=(x<<3)|(k&7) in [0,64)
//              (8 row-panels/XCD -> 2MB xb slice L2-fits), by=k>>3 in [0,24):
//              w=by>>3 (0 K,1 Q,2 V->transposed), by&=7
//  MODE 2 scores: 544 blocks, exact lower-triangle; bz=x&3
//  MODE 3 PV: 512 blocks. x=id&7: bz=x&3, bxlo=x>>2; g=id>>3 in [0,64):
//             by=g&7, bx=((7-(g>>3))<<1)|bxlo in [0,16)  [FIX r8: was 2048
//             blocks with bx up to 63 -> OOB crash]. LPT: largest kend first;
//             XCD pinned to batch -> Vt 4MB L2-resident. kend=(bx+1)*128.
template <int MODE>
__global__ __launch_bounds__(256) void gemmS(
    const unsigned short* __restrict__ A, int lda, long long sA,
    const unsigned short* __restrict__ B0, int ldb, long long sB,
    void* __restrict__ C0, int ldc, long long sC,
    const float* __restrict__ b0, const float* __restrict__ b1, const float* __restrict__ b2,
    void* __restrict__ C1, void* __restrict__ C2,
    int K, float scale)
{
  __shared__ unsigned short As[8192];   // [128][64]
  __shared__ unsigned short Bs[8192];

  const int tid = threadIdx.x;
  const int wid = tid >> 6, lane = tid & 63;
  const int wr = wid >> 1, wc = wid & 1;
  const int frow = lane & 15, fk = (lane >> 4) * 8;
  const int swz = (frow & 7) << 3;

  const int id = blockIdx.x;
  int bx, by, bz = 0, w = 0;
  if (MODE == 0) {
    const int x = id & 7, k = id >> 3;      // k in [0,192)
    bx = (x << 3) | (k & 7);                // [0,64)
    by = k >> 3;                            // [0,24)
    w = by >> 3; by &= 7;
  } else if (MODE == 2) {
    const int x = id & 7;
    bz = x & 3;
    int u = ((id >> 3) << 1) | (x >> 2);    // [0,136) triangular index
    int r = (int)((sqrtf(8.f * u + 1.f) - 1.f) * 0.5f);
    while ((r + 1) * (r + 2) / 2 <= u) ++r;
    while (r * (r + 1) / 2 > u) --r;
    bx = r; by = u - r * (r + 1) / 2;       // by <= bx
  } else {
    const int x = id & 7, g = id >> 3;      // g in [0,64)
    bz = x & 3;
    by = g & 7;
    bx = ((7 - (g >> 3)) << 1) | (x >> 2);  // [0,16), LPT: large bx first
  }

  const int brow0 = bx * 128, bcol0 = by * 128;
  const unsigned short *Ap, *Bp;
  if (MODE == 0) {
    Ap = A;
    Bp = B0 + ((size_t)w << 20);
  } else {
    Ap = A + (size_t)bz * sA;
    Bp = B0 + (size_t)bz * sB;
  }
  const int kend = (MODE == 3) ? min(K, brow0 + 128) : K;
  const int nt = kend >> 6;

  f32x4 acc[4][4];
  #pragma unroll
  for (int i = 0; i < 4; ++i)
    #pragma unroll
    for (int j = 0; j < 4; ++j) acc[i][j] = (f32x4){0.f, 0.f, 0.f, 0.f};

  #pragma unroll 1
  for (int t = 0; t < nt; ++t) {
    const int k0 = t << 6;
    // stage A,B tiles (linear LDS dest, pre-swizzled source col)
    #pragma unroll
    for (int i = 0; i < 4; ++i) {
      const int e = (i * 256 + tid) * 8;
      const int r = e >> 6, c = e & 63;
      gload_lds16(Ap + (size_t)(brow0 + r) * lda + k0 + (c ^ ((r & 7) << 3)), &As[e]);
    }
    #pragma unroll
    for (int i = 0; i < 4; ++i) {
      const int e = (i * 256 + tid) * 8;
      const int r = e >> 6, c = e & 63;
      gload_lds16(Bp + (size_t)(bcol0 + r) * ldb + k0 + (c ^ ((r & 7) << 3)), &Bs[e]);
    }
    __syncthreads();   // drains vmcnt (compiler emits full waitcnt before barrier)
    #pragma unroll
    for (int kk = 0; kk < 2; ++kk) {
      const int col = (kk * 32 + fk) ^ swz;
      bf16x8 af[4], bf[4];
      #pragma unroll
      for (int mi = 0; mi < 4; ++mi)
        af[mi] = *(const bf16x8*)&As[(wr * 64 + mi * 16 + frow) * 64 + col];
      #pragma unroll
      for (int ni = 0; ni < 4; ++ni)
        bf[ni] = *(const bf16x8*)&Bs[(wc * 64 + ni * 16 + frow) * 64 + col];
      __builtin_amdgcn_s_setprio(1);
      #pragma unroll
      for (int mi = 0; mi < 4; ++mi)
        #pragma unroll
        for (int ni = 0; ni < 4; ++ni)
          acc[mi][ni] = __builtin_amdgcn_mfma_f32_16x16x32_bf16(af[mi], bf[ni], acc[mi][ni], 0, 0, 0);
      __builtin_amdgcn_s_setprio(0);
    }
    __syncthreads();   // reads done before next stage overwrites
  }

  // epilogue: C/D layout col=lane&15, row=(lane>>4)*4+reg
  const float* bias = nullptr;
  if (MODE == 0) bias = (w == 0) ? b0 : (w == 1) ? b1 : b2;

  #pragma unroll
  for (int mi = 0; mi < 4; ++mi) {
    #pragma unroll
    for (int ni = 0; ni < 4; ++ni) {
      const int row0 = brow0 + wr * 64 + mi * 16 + (lane >> 4) * 4;
      const int col = bcol0 + wc * 64 + ni * 16 + frow;
      if (MODE == 0) {
        const float bv = bias[col];
        if (w == 2) {
          unsigned short* Cb = (unsigned short*)C2;
          const int bb = row0 >> 11, s0 = row0 & 2047;
          ushort4 pk;
          pk.x = f2bf(acc[mi][ni][0] + bv);
          pk.y = f2bf(acc[mi][ni][1] + bv);
          pk.z = f2bf(acc[mi][ni][2] + bv);
          pk.w = f2bf(acc[mi][ni][3] + bv);
          *(ushort4*)&Cb[(size_t)bb * (1024 * 2048) + (size_t)col * 2048 + s0] = pk;
        } else {
          unsigned short* Cb = (unsigned short*)(w == 0 ? C0 : C1);
          #pragma unroll
          for (int r = 0; r < 4; ++r)
            Cb[(size_t)(row0 + r) * ldc + col] = f2bf(acc[mi][ni][r] + bv);
        }
      } else if (MODE == 2) {
        unsigned short* Cb = (unsigned short*)C0 + (size_t)bz * sC;
        #pragma unroll
        for (int r = 0; r < 4; ++r)
          Cb[(size_t)(row0 + r) * ldc + col] = f2bf(acc[mi][ni][r] * scale);
      } else {
        float* Cf = (float*)C0 + (size_t)bz * sC;
        #pragma unroll
        for (int r = 0; r < 4; ++r)
          Cf[(size_t)(row0 + r) * ldc + col] = acc[mi][ni][r];
      }
    }
  }
}

// in-place causal softmax, trimmed to the 128-col-rounded causal prefix
// (PV with BM=128 reads exactly j < ((i>>7)+1)*128)
__global__ __launch_bounds__(256) void softmax_causal(unsigned short* __restrict__ Sc) {
  const int row = blockIdx.x;     // b*2048 + i
  const int i = row & 2047;
  const int nc = ((i >> 7) + 1) * 128;
  unsigned short* rp = Sc + (size_t)row * 2048;
  const int t = threadIdx.x;
  const int j0 = t * 8;
  const bool act = (j0 < nc);

  float v[8];
  if (act) {
    uint4 raw = ((const uint4*)rp)[t];
    unsigned us[8];
    us[0] = raw.x & 0xffffu; us[1] = raw.x >> 16;
    us[2] = raw.y & 0xffffu; us[3] = raw.y >> 16;
    us[4] = raw.z & 0xffffu; us[5] = raw.z >> 16;
    us[6] = raw.w & 0xffffu; us[7] = raw.w >> 16;
    #pragma unroll
    for (int e = 0; e < 8; ++e) v[e] = bf2f((unsigned short)us[e]);
  } else {
    #pragma unroll
    for (int e = 0; e < 8; ++e) v[e] = 0.f;
  }

  float m = -3.0e38f;
  if (act) {
    #pragma unroll
    for (int e = 0; e < 8; ++e) if (j0 + e <= i) m = fmaxf(m, v[e]);
  }
  #pragma unroll
  for (int o = 32; o > 0; o >>= 1) m = fmaxf(m, __shfl_xor(m, o));

  __shared__ float red[8];
  const int wid = t >> 6, lane = t & 63;
  if (lane == 0) red[wid] = m;
  __syncthreads();
  m = fmaxf(fmaxf(red[0], red[1]), fmaxf(red[2], red[3]));

  float ev[8];
  float s = 0.f;
  #pragma unroll
  for (int e = 0; e < 8; ++e) {
    float x = (act && j0 + e <= i) ? __expf(v[e] - m) : 0.f;
    ev[e] = x; s += x;
  }
  #pragma unroll
  for (int o = 32; o > 0; o >>= 1) s += __shfl_xor(s, o);
  if (lane == 0) red[4 + wid] = s;
  __syncthreads();
  s = red[4] + red[5] + red[6] + red[7];
  const float inv = 1.f / s;

  if (act) {
    uint4 outw;
    outw.x = (unsigned)f2bf(ev[0] * inv) | ((unsigned)f2bf(ev[1] * inv) << 16);
    outw.y = (unsigned)f2bf(ev[2] * inv) | ((unsigned)f2bf(ev[3] * inv) << 16);
    outw.z = (unsigned)f2bf(ev[4] * inv) | ((unsigned)f2bf(ev[5] * inv) << 16);
    outw.w = (unsigned)f2bf(ev[6] * inv) | ((unsigned)f2bf(ev[7] * inv) << 16);
    ((uint4*)rp)[t] = outw;
  }
}

// one launch converts x (2,097,152 float4) + 3 weights (262,144 float4 each)
__global__ __launch_bounds__(256) void cvt_all(
    const float4* __restrict__ x,
    const float4* __restrict__ w0, const float4* __restrict__ w1,
    const float4* __restrict__ w2,
    ushort4* __restrict__ xb, ushort4* __restrict__ wb) {
  const int idx = blockIdx.x * 256 + threadIdx.x;   // [0, 2883584)
  const float4* src; ushort4* dst; int off;
  if (idx < 2097152) { src = x; dst = xb; off = idx; }
  else {
    const int j = idx - 2097152;
    const int sel = j >> 18;                        // 262144 per weight
    src = (sel == 0) ? w0 : (sel == 1) ? w1 : w2;
    dst = wb + (size_t)sel * 262144;
    off = j & 262143;
  }
  float4 f = src[off];
  ushort4 o;
  o.x = f2bf(f.x); o.y = f2bf(f.y); o.z = f2bf(f.z); o.w = f2bf(f.w);
  dst[off] = o;
}

extern "C" void kernel_launch(void* const* d_in, const int* in_sizes, int n_in,
                              void* d_out, int out_size, void* d_ws, size_t ws_size,
                              hipStream_t stream) {
  const float* x  = (const float*)d_in[0];
  const float* Wk = (const float*)d_in[1];
  const float* bk = (const float*)d_in[2];
  const float* Wq = (const float*)d_in[3];
  const float* bq = (const float*)d_in[4];
  const float* Wv = (const float*)d_in[5];
  const float* bv = (const float*)d_in[6];
  float* out = (float*)d_out;

  char* ws = (char*)d_ws;
  unsigned short* xb = (unsigned short*)(ws + 0);          // 8192x1024 bf16  (16 MB)
  unsigned short* Wb = (unsigned short*)(ws + 16777216);   // 3 x 1024x1024   (6 MB)
  unsigned short* Kb = (unsigned short*)(ws + 23068672);   // 8192x1024       (16 MB)
  unsigned short* Qb = (unsigned short*)(ws + 39845888);   // 8192x1024       (16 MB)
  unsigned short* Vt = (unsigned short*)(ws + 56623104);   // 4 x 1024x2048   (16 MB)
  unsigned short* Sc = (unsigned short*)(ws + 73400320);   // 4 x 2048x2048   (32 MB)

  // converts (x + 3 weights, one launch)
  cvt_all<<<11264, 256, 0, stream>>>((const float4*)x, (const float4*)Wk,
                                     (const float4*)Wq, (const float4*)Wv,
                                     (ushort4*)xb, (ushort4*)Wb);

  // fused QKV: 1536 blocks, XCD-chunked row panels
  gemmS<0><<<1536, 256, 0, stream>>>(
      xb, 1024, 0, Wb, 1024, 0, Kb, 1024, 0, bk, bq, bv, Qb, Vt, 1024, 1.f);

  // scores = Q K^T / 32: exact causal lower-triangle grid (544 blocks)
  gemmS<2><<<544, 256, 0, stream>>>(
      Qb, 1024, 2048LL * 1024, Kb, 1024, 2048LL * 1024,
      Sc, 2048, 2048LL * 2048, nullptr, nullptr, nullptr, nullptr, nullptr, 1024, 0.03125f);

  softmax_causal<<<8192, 256, 0, stream>>>(Sc);

  // out = P @ V: 512 blocks, LPT, XCD-pinned batch (Vt L2-resident)
  gemmS<3><<<512, 256, 0, stream>>>(
      Sc, 2048, 2048LL * 2048, Vt, 2048, 1024LL * 2048,
      out, 1024, 2048LL * 1024, nullptr, nullptr, nullptr, nullptr, nullptr, 2048, 1.f);
}